// Round 4
// baseline (369.535 us; speedup 1.0000x reference)
//
#include <hip/hip_runtime.h>
#include <stdint.h>

#define B_ 4
#define C_ 256
#define N_ 4096
#define L2E 1.4426950408889634f

typedef unsigned short u16;
typedef unsigned int u32;
typedef float f32x4 __attribute__((ext_vector_type(4)));
typedef __bf16 bf16x8 __attribute__((ext_vector_type(8)));

union U16x8 { uint4 q; bf16x8 v; u16 u[8]; __bf16 h[8]; };
union BF2 { u32 w; __bf16 h[2]; };

__device__ __forceinline__ bf16x8 ld_bf8(const u16* p) {
  U16x8 t; t.q = *(const uint4*)p; return t.v;
}
__device__ __forceinline__ f32x4 mfma16(bf16x8 a, bf16x8 b, f32x4 c) {
  return __builtin_amdgcn_mfma_f32_16x16x32_bf16(a, b, c, 0, 0, 0);
}

// ---------------- K-prep: weight conversions ----------------
__global__ __launch_bounds__(256) void k_prep(const float* __restrict__ vw, const float* __restrict__ tw,
                                              const float* __restrict__ qkw,
                                              u16* __restrict__ wv, u16* __restrict__ wt, float* __restrict__ wqkt) {
  int i = blockIdx.x * 256 + threadIdx.x;
  int stride = gridDim.x * 256;
  for (int idx = i; idx < C_ * C_; idx += stride) {
    BF2 a, b; a.h[0] = (__bf16)vw[idx]; b.h[0] = (__bf16)tw[idx];
    wv[idx] = (u16)(a.w & 0xFFFF);
    wt[idx] = (u16)(b.w & 0xFFFF);
  }
  for (int idx = i; idx < 32 * C_; idx += stride) {
    int c = idx >> 8, cin = idx & 255;
    wqkt[cin * 32 + c] = qkw[idx];           // transposed, fp32 (exponent-accuracy path)
  }
}

// ---------------- K-xt: x [b][c][n] fp32 -> x_t [b][n][c] bf16 ----------------
__global__ __launch_bounds__(256) void k_xt(const float* __restrict__ x, u16* __restrict__ xt) {
  int bid = blockIdx.x;
  int cb = bid & 3, nt = (bid >> 2) & 63, b = bid >> 8;
  __shared__ u16 tile[64][66];
  int t = threadIdx.x, nl = t & 63, cg = t >> 6;
  const float* xp = x + ((size_t)b * C_ + cb * 64) * N_ + nt * 64;
  #pragma unroll
  for (int cc = 0; cc < 16; ++cc) {
    int c = cg * 16 + cc;
    BF2 v; v.h[0] = (__bf16)xp[(size_t)c * N_ + nl];
    tile[c][nl] = (u16)(v.w & 0xFFFF);
  }
  __syncthreads();
  u16* op = xt + ((size_t)b * N_ + nt * 64) * C_ + cb * 64;
  #pragma unroll
  for (int nn = 0; nn < 16; ++nn) {
    int n2 = cg * 16 + nn;
    op[(size_t)n2 * C_ + nl] = tile[nl][n2];
  }
}

// ---------------- K-qk: fp32 GEMM + bn1/bn2 + relu -> q',k' bf16 [b][n][32] ----------------
// qsg = (sum_c q) * log2(e)  [scaled domain for exp2]; ksg = sum_c k (raw).
__global__ __launch_bounds__(256) void k_qk(
    const float* __restrict__ x, const float* __restrict__ wqkt,
    const float* __restrict__ bn1s, const float* __restrict__ bn1b,
    const float* __restrict__ bn2s, const float* __restrict__ bn2b,
    u16* __restrict__ qb, u16* __restrict__ kb,
    float* __restrict__ qsg, float* __restrict__ ksg) {
  int bid = blockIdx.x;
  bid = (bid & 7) * 32 + (bid >> 3);
  int nt = bid & 63, b = bid >> 6;
  int t = threadIdx.x;
  int nl = t & 63;
  int qg = __builtin_amdgcn_readfirstlane(t >> 6);
  int n = nt * 64 + nl;

  __shared__ float red[4][64][33];
  __shared__ float qsum[4][64], ksum[4][64];

  float acc[32];
  #pragma unroll
  for (int c = 0; c < 32; ++c) acc[c] = 0.f;

  const float* xp = x + ((size_t)b * C_ + qg * 64) * N_ + n;
  const float* wp = wqkt + qg * 64 * 32;
  for (int i = 0; i < 64; ++i) {
    float xvv = xp[(size_t)i * N_];
    const float* wr = wp + i * 32;
    #pragma unroll
    for (int c = 0; c < 32; ++c) acc[c] = fmaf(wr[c], xvv, acc[c]);
  }
  #pragma unroll
  for (int c = 0; c < 32; ++c) red[qg][nl][c] = acc[c];
  __syncthreads();

  float pqs = 0.f, pks = 0.f;
  U16x8 tq, tk;
  #pragma unroll
  for (int i2 = 0; i2 < 8; ++i2) {
    int c = qg * 8 + i2;
    float s = red[0][nl][c] + red[1][nl][c] + red[2][nl][c] + red[3][nl][c];
    float fq = fmaxf(fmaf(s, bn1s[c], bn1b[c]), 0.f);
    float fk = fmaxf(fmaf(s, bn2s[c], bn2b[c]), 0.f);
    pqs += fq; pks += fk;
    tq.h[i2] = (__bf16)fq; tk.h[i2] = (__bf16)fk;
  }
  size_t ofs = ((size_t)(b * N_ + n)) * 32 + qg * 8;
  *(uint4*)(qb + ofs) = tq.q;
  *(uint4*)(kb + ofs) = tk.q;

  qsum[qg][nl] = pqs; ksum[qg][nl] = pks;
  __syncthreads();
  if (t < 64) {
    int nn2 = nt * 64 + t;
    qsg[b * N_ + nn2] = (qsum[0][t] + qsum[1][t] + qsum[2][t] + qsum[3][t]) * L2E;
    ksg[b * N_ + nn2] = ksum[0][t] + ksum[1][t] + ksum[2][t] + ksum[3][t];
  }
}

// ---------------- K-gemm256: out[o][n] = epilogue(W[256x256] @ act^T) ----------------
// MODE 0: v-conv -> x_v bf16 [b][c][n'] with n' k-slot-permuted within each 32-block
//         (n = s*16+g*4+t -> n' = g*8+s*4+t) so phaseB's PV A-fragment is one 16B load.
// MODE 1: trans-conv + residual -> out fp32
template<int MODE>
__global__ __launch_bounds__(256) void k_gemm256(
    const u16* __restrict__ W, const u16* __restrict__ act,
    const float* __restrict__ bias, const float* __restrict__ bns, const float* __restrict__ bnb,
    const float* __restrict__ xres, u16* __restrict__ outb, float* __restrict__ outf) {
  int bid = blockIdx.x;
  bid = (bid & 7) * 64 + (bid >> 3);
  int nt = bid & 127, b = bid >> 7;
  int n0 = nt * 32;
  int t = threadIdx.x;
  int w = t >> 6, l = t & 63, lr = l & 15, lg = l >> 4;

  f32x4 acc[4][2];
  #pragma unroll
  for (int ot = 0; ot < 4; ++ot)
    #pragma unroll
    for (int ns = 0; ns < 2; ++ns) acc[ot][ns] = f32x4{0.f, 0.f, 0.f, 0.f};

  const u16* actp = act + ((size_t)b * N_ + n0) * C_;
  for (int kk = 0; kk < 8; ++kk) {
    int k0 = kk * 32;
    bf16x8 bf[2];
    #pragma unroll
    for (int ns = 0; ns < 2; ++ns)
      bf[ns] = ld_bf8(actp + (size_t)(ns * 16 + lr) * C_ + k0 + lg * 8);
    #pragma unroll
    for (int ot = 0; ot < 4; ++ot) {
      bf16x8 af = ld_bf8(W + (size_t)(w * 64 + ot * 16 + lr) * C_ + k0 + lg * 8);
      #pragma unroll
      for (int ns = 0; ns < 2; ++ns) acc[ot][ns] = mfma16(af, bf[ns], acc[ot][ns]);
    }
  }
  #pragma unroll
  for (int ot = 0; ot < 4; ++ot) {
    #pragma unroll
    for (int r = 0; r < 4; ++r) {
      int oc = w * 64 + ot * 16 + lg * 4 + r;
      float sO = bns[oc], bO = bnb[oc], biO = bias[oc];
      #pragma unroll
      for (int ns = 0; ns < 2; ++ns) {
        int nn = ns * 16 + lr;
        float val = fmaxf(fmaf(acc[ot][ns][r] + biO, sO, bO), 0.f);
        if (MODE == 0) {
          int np = ((nn >> 2) & 3) * 8 + (nn >> 4) * 4 + (nn & 3);   // k-slot permute
          size_t idx = ((size_t)b * C_ + oc) * N_ + n0 + np;
          BF2 v; v.h[0] = (__bf16)val; outb[idx] = (u16)(v.w & 0xFFFF);
        } else {
          size_t idx = ((size_t)b * C_ + oc) * N_ + n0 + nn;
          outf[idx] = xres[idx] + val;
        }
      }
    }
  }
}

// ---------------- K-phaseA: fused row stat rmg = max' + log2(sum') (scaled domain) ----------------
__global__ __launch_bounds__(512) void k_phaseA(
    const u16* __restrict__ qb, const u16* __restrict__ kb,
    const float* __restrict__ qsg, const float* __restrict__ ksg,
    float* __restrict__ rmg) {
  int bid = blockIdx.x;
  bid = (bid & 7) * 64 + (bid >> 3);
  int nt = bid & 127, b = bid >> 7;
  int bN = b * N_;
  int t = threadIdx.x;
  int w = t >> 6, l = t & 63, lr = l & 15, lg = l >> 4;
  int nsub = w & 1, mq = w >> 1;
  int nrow0 = nt * 32 + nsub * 16;

  __shared__ float pM[4][32], pS[4][32];

  bf16x8 qf = ld_bf8(qb + ((size_t)(bN + nrow0 + lr)) * 32 + lg * 8);
  f32x4 qsv = *(const f32x4*)(qsg + bN + nrow0 + lg * 4);   // already *L2E

  float Mv[4], Sv[4];
  #pragma unroll
  for (int r = 0; r < 4; ++r) { Mv[r] = -3e38f; Sv[r] = 0.f; }

  int mbase = mq * 1024;
  for (int ms = 0; ms < 16; ++ms) {
    float ev[4][4];
    #pragma unroll
    for (int mt2 = 0; mt2 < 4; ++mt2) {
      int m0 = mbase + ms * 64 + mt2 * 16;
      bf16x8 kf = ld_bf8(kb + ((size_t)(bN + m0 + lr)) * 32 + lg * 8);
      f32x4 e = mfma16(qf, kf, f32x4{0.f, 0.f, 0.f, 0.f});
      float ksv = ksg[bN + m0 + lr];
      #pragma unroll
      for (int r = 0; r < 4; ++r) ev[mt2][r] = fmaf(e[r], L2E, -qsv[r] * ksv);  // scaled e'
    }
    #pragma unroll
    for (int r = 0; r < 4; ++r) {
      float t0 = fmaxf(fmaxf(ev[0][r], ev[1][r]), fmaxf(ev[2][r], ev[3][r]));
      float Mn = fmaxf(Mv[r], t0);
      Sv[r] = Sv[r] * __builtin_amdgcn_exp2f(Mv[r] - Mn)
            + __builtin_amdgcn_exp2f(ev[0][r] - Mn)
            + __builtin_amdgcn_exp2f(ev[1][r] - Mn)
            + __builtin_amdgcn_exp2f(ev[2][r] - Mn)
            + __builtin_amdgcn_exp2f(ev[3][r] - Mn);
      Mv[r] = Mn;
    }
  }
  #pragma unroll
  for (int off = 1; off < 16; off <<= 1) {
    #pragma unroll
    for (int r = 0; r < 4; ++r) {
      float Mo = __shfl_xor(Mv[r], off);
      float So = __shfl_xor(Sv[r], off);
      float Mn = fmaxf(Mv[r], Mo);
      Sv[r] = Sv[r] * __builtin_amdgcn_exp2f(Mv[r] - Mn)
            + So   * __builtin_amdgcn_exp2f(Mo   - Mn);
      Mv[r] = Mn;
    }
  }
  if (lr == 0) {
    #pragma unroll
    for (int r = 0; r < 4; ++r) {
      pM[mq][nsub * 16 + lg * 4 + r] = Mv[r];
      pS[mq][nsub * 16 + lg * 4 + r] = Sv[r];
    }
  }
  __syncthreads();
  if (t < 32) {
    float M = fmaxf(fmaxf(pM[0][t], pM[1][t]), fmaxf(pM[2][t], pM[3][t]));
    float S = pS[0][t] * __builtin_amdgcn_exp2f(pM[0][t] - M)
            + pS[1][t] * __builtin_amdgcn_exp2f(pM[1][t] - M)
            + pS[2][t] * __builtin_amdgcn_exp2f(pM[2][t] - M)
            + pS[3][t] * __builtin_amdgcn_exp2f(pM[3][t] - M);
    rmg[bN + nt * 32 + t] = M + __builtin_amdgcn_logf(S);   // v_log_f32 = log2
  }
}

// ---------------- K-phaseB: barrier-free, LDS-free flash PV ----------------
// 256 blocks (m64) x 512 thr; 8 waves = 4 msub x 2 chalf; wave = m16 x c128 x all n.
// Per 32-n window: 2 e-MFMA -> 8 exp (fp32 rank-1 + fused stat) -> one pb B-frag
// -> 8 PV MFMA (c128). exp chain amortized over 2x the MFMA vs round-3.
struct Win {
  bf16x8 qf0, qf1;
  f32x4 qs0, qs1, rm0, rm1;
  uint4 vq[8];
};

__global__ __launch_bounds__(512, 2) void k_phaseB(
    const u16* __restrict__ qb, const u16* __restrict__ kb,
    const float* __restrict__ qsg, const float* __restrict__ ksg,
    const float* __restrict__ rmg,
    const u16* __restrict__ xvp, const u16* __restrict__ xt,
    u16* __restrict__ diffb) {
  int bid = blockIdx.x;
  bid = (bid & 7) * 32 + (bid >> 3);     // XCD swizzle: each XCD = half a batch (2MB V panel in its L2)
  int mt = bid & 63, b = bid >> 6;
  int m0 = mt * 64;
  int bN = b * N_;
  int t = threadIdx.x;
  int w = t >> 6, l = t & 63, lr = l & 15, lg = l >> 4;
  int msub = w & 3, chalf = w >> 2;
  int mbase = m0 + msub * 16;
  int c0 = chalf * 128;

  bf16x8 kf = ld_bf8(kb + (size_t)(bN + mbase + lr) * 32 + lg * 8);
  float ks = ksg[bN + mbase + lr];

  const u16* qbase = qb + (size_t)bN * 32;
  const float* qsb = qsg + bN;
  const float* rmb = rmg + bN;
  const u16* vbase = xvp + (size_t)(b * C_ + c0 + lr) * N_ + lg * 8;

  f32x4 acc[8];
  #pragma unroll
  for (int ct = 0; ct < 8; ++ct) acc[ct] = f32x4{0.f, 0.f, 0.f, 0.f};
  float cs = 0.f;

  auto load_win = [&](int wd) {
    Win W;
    int nb = wd * 32;
    W.qf0 = ld_bf8(qbase + (size_t)(nb + lr) * 32 + lg * 8);
    W.qf1 = ld_bf8(qbase + (size_t)(nb + 16 + lr) * 32 + lg * 8);
    W.qs0 = *(const f32x4*)(qsb + nb + lg * 4);
    W.qs1 = *(const f32x4*)(qsb + nb + 16 + lg * 4);
    W.rm0 = *(const f32x4*)(rmb + nb + lg * 4);
    W.rm1 = *(const f32x4*)(rmb + nb + 16 + lg * 4);
    #pragma unroll
    for (int ct = 0; ct < 8; ++ct)
      W.vq[ct] = *(const uint4*)(vbase + (size_t)(ct * 16) * N_ + nb);
    return W;
  };

  Win cur = load_win(0);
  for (int wd = 0; wd < 128; ++wd) {
    Win nxt = load_win(wd < 127 ? wd + 1 : 127);   // depth-1 prefetch

    f32x4 e0 = mfma16(cur.qf0, kf, f32x4{0.f, 0.f, 0.f, 0.f});  // [n sub0 rows][m col=lr]
    f32x4 e1 = mfma16(cur.qf1, kf, f32x4{0.f, 0.f, 0.f, 0.f});  // [n sub1 rows][m col=lr]

    float p0[4], p1[4];
    #pragma unroll
    for (int r = 0; r < 4; ++r) {
      p0[r] = __builtin_amdgcn_exp2f(fmaf(cur.qs0[r], -ks, fmaf(e0[r], L2E, -cur.rm0[r])));
      p1[r] = __builtin_amdgcn_exp2f(fmaf(cur.qs1[r], -ks, fmaf(e1[r], L2E, -cur.rm1[r])));
    }
    cs += ((p0[0] + p0[1]) + (p0[2] + p0[3])) + ((p1[0] + p1[1]) + (p1[2] + p1[3]));

    U16x8 pb;   // B-frag k-slots (permuted layout matches xvp storage)
    #pragma unroll
    for (int r = 0; r < 4; ++r) { pb.h[r] = (__bf16)p0[r]; pb.h[4 + r] = (__bf16)p1[r]; }

    #pragma unroll
    for (int ct = 0; ct < 8; ++ct) {
      U16x8 vv; vv.q = cur.vq[ct];
      acc[ct] = mfma16(vv.v, pb.v, acc[ct]);
    }
    cur = nxt;
  }

  // colsum: lane holds m = mbase+lr partials over lg-disjoint n subsets
  cs += __shfl_xor(cs, 16);
  cs += __shfl_xor(cs, 32);
  float inv = __builtin_amdgcn_rcpf(1e-9f + cs);

  // epilogue: diff = x - acc*inv, bf16 [b][n][c]; lane (lr,lg): n-row m=mbase+lr, c=c0+ct*16+lg*4+r
  #pragma unroll
  for (int ct = 0; ct < 8; ++ct) {
    size_t base = ((size_t)(bN + mbase + lr)) * C_ + c0 + ct * 16 + lg * 4;
    uint2 xv2 = *(const uint2*)(xt + base);
    BF2 xa, xb; xa.w = xv2.x; xb.w = xv2.y;
    BF2 o0, o1;
    o0.h[0] = (__bf16)((float)xa.h[0] - acc[ct][0] * inv);
    o0.h[1] = (__bf16)((float)xa.h[1] - acc[ct][1] * inv);
    o1.h[0] = (__bf16)((float)xb.h[0] - acc[ct][2] * inv);
    o1.h[1] = (__bf16)((float)xb.h[1] - acc[ct][3] * inv);
    uint2 ov; ov.x = o0.w; ov.y = o1.w;
    *(uint2*)(diffb + base) = ov;
  }
}

// ---------------- launch ----------------
extern "C" void kernel_launch(void* const* d_in, const int* in_sizes, int n_in,
                              void* d_out, int out_size, void* d_ws, size_t ws_size,
                              hipStream_t stream) {
  const float* x       = (const float*)d_in[0];
  const float* qk_w    = (const float*)d_in[1];
  const float* v_w     = (const float*)d_in[2];
  const float* v_b     = (const float*)d_in[3];
  const float* trans_w = (const float*)d_in[4];
  const float* trans_b = (const float*)d_in[5];
  const float* bn1s = (const float*)d_in[6];
  const float* bn1b = (const float*)d_in[7];
  const float* bn2s = (const float*)d_in[8];
  const float* bn2b = (const float*)d_in[9];
  const float* bn3s = (const float*)d_in[10];
  const float* bn3b = (const float*)d_in[11];
  const float* ans  = (const float*)d_in[12];
  const float* anb  = (const float*)d_in[13];
  float* out = (float*)d_out;
  char* ws = (char*)d_ws;

  if (ws_size < 27820032) return;

  u16*   xt    = (u16*)(ws + 0);          // [B][N][C] bf16   8 MB
  u16*   xvp   = (u16*)(ws + 8388608);    // [B][C][N'] bf16  8 MB (k-slot permuted)
  u16*   diffb = (u16*)(ws + 16777216);   // [B][N][C] bf16   8 MB
  u16*   qb    = (u16*)(ws + 25165824);   // [B][N][32] bf16  1 MB
  u16*   kb    = (u16*)(ws + 26214400);   // [B][N][32] bf16  1 MB
  u16*   wv    = (u16*)(ws + 27262976);
  u16*   wt    = (u16*)(ws + 27394048);
  float* wqkt  = (float*)(ws + 27525120);
  float* qsg   = (float*)(ws + 27557888);
  float* ksg   = (float*)(ws + 27623424);
  float* rmg   = (float*)(ws + 27688960);

  k_prep<<<64, 256, 0, stream>>>(v_w, trans_w, qk_w, wv, wt, wqkt);
  k_xt<<<1024, 256, 0, stream>>>(x, xt);
  k_qk<<<256, 256, 0, stream>>>(x, wqkt, bn1s, bn1b, bn2s, bn2b, qb, kb, qsg, ksg);
  k_gemm256<0><<<512, 256, 0, stream>>>(wv, xt, v_b, bn3s, bn3b, nullptr, xvp, nullptr);
  k_phaseA<<<512, 512, 0, stream>>>(qb, kb, qsg, ksg, rmg);
  k_phaseB<<<256, 512, 0, stream>>>(qb, kb, qsg, ksg, rmg, xvp, xt, diffb);
  k_gemm256<1><<<512, 256, 0, stream>>>(wt, diffb, trans_b, ans, anb, x, nullptr, out);
}